// Round 12
// baseline (161.710 us; speedup 1.0000x reference)
//
#include <hip/hip_runtime.h>

#define TT 48
#define DD 32
#define HH 64
#define BB 16384
#define LOG2E 1.4426950408889634f

typedef __bf16 bf16x8 __attribute__((ext_vector_type(8)));
typedef float f32x4 __attribute__((ext_vector_type(4)));

#define MFMA(a, b, c) __builtin_amdgcn_mfma_f32_16x16x32_bf16(a, b, c, 0, 0, 0)
#define BC(v) __builtin_bit_cast(bf16x8, v)

static __device__ __forceinline__ float exp2_f(float v) {
#if __has_builtin(__builtin_amdgcn_exp2f)
  return __builtin_amdgcn_exp2f(v);
#else
  return exp2f(v);
#endif
}
static __device__ __forceinline__ unsigned short bfu(float f) {
  __bf16 b = (__bf16)f;
  return __builtin_bit_cast(unsigned short, b);
}
static __device__ __forceinline__ float bff(unsigned short u) {
  return (float)__builtin_bit_cast(__bf16, u);
}
// pre-scaled domain (y = x*log2e): sigmoid(x) = rcp(1 + 2^-y)
static __device__ __forceinline__ float sigm2(float y) {
  return __builtin_amdgcn_rcpf(1.f + exp2_f(-y));
}
// pre-scaled domain (y = 2x*log2e): tanh(x) = 1 - 2*rcp(1 + 2^y)
static __device__ __forceinline__ float tanh2(float y) {
  return fmaf(-2.f, __builtin_amdgcn_rcpf(1.f + exp2_f(y)), 1.f);
}

// ------------------------------------------------------------------
// Row bijection: tile m = g*4+hq (g = gate), tile-row = qp*4+r.
//   hidx(hq,qp,r) = (hq>>1)*32 + qp*8 + (hq&1)*4 + r
// Lane (b,qp)'s D outputs {hidx(hq,qp,r)} == exactly its next-step
// B-fragment slots {c*32+qp*8+j} -> h NEVER leaves the lane: zero
// LDS / shuffle / barrier in the recurrence.
// ------------------------------------------------------------------

// Kernel 0: linearize W into per-lane MFMA A-fragment order, pre-scaled into
// the exp2 domain: i/f/o rows (and bias) * log2e, g rows * 2*log2e.
__global__ void prep_kernel(const float* __restrict__ W_ih, const float* __restrict__ W_hh,
                            const float* __restrict__ b_ih, const float* __restrict__ b_hh,
                            unsigned short* __restrict__ WhhL, unsigned short* __restrict__ WihL,
                            float* __restrict__ bsumL) {
  const int tid = threadIdx.x;  // 256 threads, 1 block
  const int l = tid & 63, qt = tid >> 6;
  const int rowl = l & 15, kq = (l >> 4) * 8;
  for (int mm = 0; mm < 4; ++mm) {
    const int m = qt * 4 + mm;
    const int g = m >> 2, hq = m & 3;
    const float s = (g == 2) ? 2.f * LOG2E : LOG2E;
    const int hidx = (hq >> 1) * 32 + (rowl >> 2) * 8 + (hq & 1) * 4 + (rowl & 3);
    const int orig = g * 64 + hidx;
    for (int c = 0; c < 2; ++c)
      for (int j = 0; j < 8; ++j) {
        float w = W_hh[orig * 64 + c * 32 + kq + j] * s;
        unsigned short hi = bfu(w);
        WhhL[((0 * 16 + m) * 2 + c) * 512 + l * 8 + j] = hi;
        WhhL[((1 * 16 + m) * 2 + c) * 512 + l * 8 + j] = bfu(w - bff(hi));
      }
    for (int j = 0; j < 8; ++j)
      WihL[m * 512 + l * 8 + j] = bfu(W_ih[orig * 32 + kq + j] * s);
    if ((l >> 4) == 0) bsumL[m * 16 + rowl] = (b_ih[orig] + b_hh[orig]) * s;
  }
}

// ------------------------------------------------------------------
// Kernel 1: attention. a[b,:] = softmax_d( sum_t x[b,t,d]*w_att[2H+t] )
// (h/c/b_att terms are uniform over d -> softmax-invariant -> dropped).
// ------------------------------------------------------------------
__global__ __launch_bounds__(256) void attn_kernel(const float* __restrict__ x,
                                                   const float* __restrict__ W_att,
                                                   float* __restrict__ out0) {
  int tid = threadIdx.x;
  int b = blockIdx.x * 32 + (tid >> 3);
  int dq = (tid & 7) * 4;
  const float* xb = x + (size_t)b * (TT * DD);
  float px = 0.f, py = 0.f, pz = 0.f, pw = 0.f;
#pragma unroll 4
  for (int t = 0; t < TT; ++t) {
    float w = W_att[2 * HH + t];
    float4 xv = *(const float4*)(xb + t * DD + dq);
    px = fmaf(xv.x, w, px);
    py = fmaf(xv.y, w, py);
    pz = fmaf(xv.z, w, pz);
    pw = fmaf(xv.w, w, pw);
  }
  float m = fmaxf(fmaxf(px, py), fmaxf(pz, pw));
#pragma unroll
  for (int s = 1; s < 8; s <<= 1) m = fmaxf(m, __shfl_xor(m, s));
  float ex = __expf(px - m), ey = __expf(py - m), ez = __expf(pz - m), ew = __expf(pw - m);
  float sum = ex + ey + ez + ew;
#pragma unroll
  for (int s = 1; s < 8; s <<= 1) sum += __shfl_xor(sum, s);
  float inv = __builtin_amdgcn_rcpf(sum);
  float4 a;
  a.x = ex * inv; a.y = ey * inv; a.z = ez * inv; a.w = ew * inv;
  float* o = out0 + (size_t)b * (TT * DD) + dq;
#pragma unroll 4
  for (int t = 0; t < TT; ++t) *(float4*)(o + t * DD) = a;
}

// ------------------------------------------------------------------
// Kernel 2: lane-local LSTM, barrier-free, zero LDS. 256 blocks x 256 thr
// = 4 waves/CU (1/SIMD, gremlin-safe). Each wave owns 16 batch rows
// end-to-end; h stays in-lane via the row bijection. Register plan
// (512/wave at 1 wave/SIMD): whhHi 128 VGPR ("+v" pinned); whhLo 128 +
// wih 64 + bias 64 = 256 AGPR ("+a" pinned) used DIRECTLY as MFMA
// operands (A from AGPR; bias as srcC of the first MFMA — srcC and vdst
// are separate fields, so no accvgpr copies). Split precision
// (Whi+Wlo)*h_bf16 + Wih*xw; pointwise in exp2 domain.
// ------------------------------------------------------------------
__global__ __launch_bounds__(256, 1) void lstm_kernel(
    const float* __restrict__ x, const float* __restrict__ h0, const float* __restrict__ c0,
    const float* __restrict__ a_src, const unsigned short* __restrict__ WhhL,
    const unsigned short* __restrict__ WihL, const float* __restrict__ bsumL,
    float* __restrict__ out1) {
  const int tid = threadIdx.x;
  const int l = tid & 63;
  const int wid = tid >> 6;
  const int b = l & 15;
  const int qp = l >> 4;
  const int brow = blockIdx.x * 64 + wid * 16 + b;

  // resident weights: hi -> VGPR; lo, wih, bias -> AGPR
  f32x4 whhHi[16][2], whhLo[16][2], wihR[16], biasR[16];
#pragma unroll
  for (int m = 0; m < 16; ++m) {
#pragma unroll
    for (int c = 0; c < 2; ++c) {
      whhHi[m][c] = *(const f32x4*)(WhhL + (((0 * 16 + m) * 2 + c) << 9) + l * 8);
      whhLo[m][c] = *(const f32x4*)(WhhL + (((1 * 16 + m) * 2 + c) << 9) + l * 8);
    }
    wihR[m] = *(const f32x4*)(WihL + (m << 9) + l * 8);
    biasR[m] = *(const f32x4*)(bsumL + m * 16 + qp * 4);
  }
#pragma unroll
  for (int m = 0; m < 16; ++m) {
#pragma unroll
    for (int c = 0; c < 2; ++c) {
      asm volatile("" : "+v"(whhHi[m][c]));
      asm volatile("" : "+a"(whhLo[m][c]));
    }
    asm volatile("" : "+a"(wihR[m]));
    asm volatile("" : "+a"(biasR[m]));
  }

  // attention weights for this lane's d-slots (d = qp*8 + j)
  float av[8];
  {
    const float* ap = a_src + (size_t)brow * (TT * DD) + qp * 8;
    float4 a0 = *(const float4*)ap, a1 = *(const float4*)(ap + 4);
    av[0] = a0.x; av[1] = a0.y; av[2] = a0.z; av[3] = a0.w;
    av[4] = a1.x; av[5] = a1.y; av[6] = a1.z; av[7] = a1.w;
  }

  // c state: creg[hq][r] = c[brow][hidx(hq,qp,r)]
  f32x4 creg[4];
#pragma unroll
  for (int hq = 0; hq < 4; ++hq)
    creg[hq] = *(const f32x4*)(c0 + (size_t)brow * HH + (hq >> 1) * 32 + qp * 8 + (hq & 1) * 4);

  // h state as single-bf16 B-fragments: bh[c] elem j = bf16(h[brow][c*32+qp*8+j])
  bf16x8 bh[2];
#pragma unroll
  for (int c = 0; c < 2; ++c) {
    const float* hp = h0 + (size_t)brow * HH + c * 32 + qp * 8;
    float4 v0 = *(const float4*)hp, v1 = *(const float4*)(hp + 4);
    float vv[8] = {v0.x, v0.y, v0.z, v0.w, v1.x, v1.y, v1.z, v1.w};
#pragma unroll
    for (int j = 0; j < 8; ++j) bh[c][j] = (__bf16)vv[j];
  }

  const float* xp = x + (size_t)brow * (TT * DD) + qp * 8;
  float* op = out1 + (size_t)brow * (TT * HH);
  float xv[8];
  {
    float4 x0 = *(const float4*)xp, x1 = *(const float4*)(xp + 4);
    xv[0] = x0.x; xv[1] = x0.y; xv[2] = x0.z; xv[3] = x0.w;
    xv[4] = x1.x; xv[5] = x1.y; xv[6] = x1.z; xv[7] = x1.w;
  }

  for (int t = 0; t < TT; ++t) {
    // xw for this step (single bf16; lo negligible at |a*x|~0.03)
    bf16x8 bxw;
#pragma unroll
    for (int j = 0; j < 8; ++j) bxw[j] = (__bf16)(xv[j] * av[j]);
    // prefetch next x (clamped; final load is dead but harmless)
    const int tn = (t + 1 < TT) ? (t + 1) : (TT - 1);
    float xn[8];
    {
      const float* xnp = xp + (size_t)tn * DD;
      float4 x0 = *(const float4*)xnp, x1 = *(const float4*)(xnp + 4);
      xn[0] = x0.x; xn[1] = x0.y; xn[2] = x0.z; xn[3] = x0.w;
      xn[4] = x1.x; xn[5] = x1.y; xn[6] = x1.z; xn[7] = x1.w;
    }

    bf16x8 nbh[2];
#pragma unroll
    for (int hq = 0; hq < 4; ++hq) {
      f32x4 acc[4];
#pragma unroll
      for (int g = 0; g < 4; ++g) {
        const int m = g * 4 + hq;
        // first MFMA: C-operand = bias directly from AGPR, D -> VGPR
        f32x4 A = MFMA(BC(whhHi[m][0]), bh[0], biasR[m]);
        A = MFMA(BC(whhLo[m][0]), bh[0], A);  // k 0..31:  Wlo*h
        A = MFMA(BC(whhHi[m][1]), bh[1], A);  // k 32..63: Whi*h
        A = MFMA(BC(whhLo[m][1]), bh[1], A);  //           Wlo*h
        A = MFMA(BC(wihR[m]), bxw, A);        // input chunk (AGPR A-operand)
        acc[g] = A;
      }
      // pointwise: i/f/g/o lane-local (rows qp*4+r of tiles g*4+hq)
      float hr[4];
#pragma unroll
      for (int r = 0; r < 4; ++r) {
        float ig = sigm2(acc[0][r]);
        float fg = sigm2(acc[1][r]);
        float gt = tanh2(acc[2][r]);   // g rows pre-scaled by 2*log2e
        float og = sigm2(acc[3][r]);
        float cn = fg * creg[hq][r] + ig * gt;
        creg[hq][r] = cn;
        hr[r] = og * tanh2(2.f * LOG2E * cn);
      }
      // out1: contiguous float4 at hidx base (4 qp-lanes cover the full row)
      float4 hv;
      hv.x = hr[0]; hv.y = hr[1]; hv.z = hr[2]; hv.w = hr[3];
      *(float4*)(op + (size_t)t * HH + (hq >> 1) * 32 + qp * 8 + (hq & 1) * 4) = hv;
      // repack into next step's B-fragment (lane-local, single bf16)
#pragma unroll
      for (int r = 0; r < 4; ++r) nbh[hq >> 1][(hq & 1) * 4 + r] = (__bf16)hr[r];
    }
    bh[0] = nbh[0];
    bh[1] = nbh[1];
#pragma unroll
    for (int j = 0; j < 8; ++j) xv[j] = xn[j];
  }
}

extern "C" void kernel_launch(void* const* d_in, const int* in_sizes, int n_in,
                              void* d_out, int out_size, void* d_ws, size_t ws_size,
                              hipStream_t stream) {
  const float* x = (const float*)d_in[0];
  const float* h0 = (const float*)d_in[1];
  const float* c0 = (const float*)d_in[2];
  const float* W_att = (const float*)d_in[3];
  // d_in[4] = b_att: uniform shift, softmax-invariant -> unused
  const float* W_ih = (const float*)d_in[5];
  const float* W_hh = (const float*)d_in[6];
  const float* b_ih = (const float*)d_in[7];
  const float* b_hh = (const float*)d_in[8];

  float* out0 = (float*)d_out;                // attention [B,T,D]
  float* out1 = out0 + (size_t)BB * TT * DD;  // input_encoded [B,T,H]

  char* ws = (char*)d_ws;
  unsigned short* WhhL = (unsigned short*)ws;            // 65536 B
  unsigned short* WihL = (unsigned short*)(ws + 65536);  // 16384 B
  float* bsumL = (float*)(ws + 81920);                   // 1024 B

  prep_kernel<<<1, 256, 0, stream>>>(W_ih, W_hh, b_ih, b_hh, WhhL, WihL, bsumL);
  attn_kernel<<<BB / 32, 256, 0, stream>>>(x, W_att, out0);
  // lstm reads a[b,d] from the t=0 slice of out0 (== a broadcast over t)
  lstm_kernel<<<BB / 64, 256, 0, stream>>>(x, h0, c0, out0, WhhL, WihL, bsumL, out1);
}

// Round 13
// 146.118 us; speedup vs baseline: 1.1067x; 1.1067x over previous
//
#include <hip/hip_runtime.h>

#define TT 48
#define DD 32
#define HH 64
#define BB 16384
#define LOG2E 1.4426950408889634f

typedef __bf16 bf16x8 __attribute__((ext_vector_type(8)));
typedef float f32x4 __attribute__((ext_vector_type(4)));

#define MFMA(a, b, c) __builtin_amdgcn_mfma_f32_16x16x32_bf16(a, b, c, 0, 0, 0)
#define BC(v) __builtin_bit_cast(bf16x8, v)

static __device__ __forceinline__ float exp2_f(float v) {
#if __has_builtin(__builtin_amdgcn_exp2f)
  return __builtin_amdgcn_exp2f(v);
#else
  return exp2f(v);
#endif
}
static __device__ __forceinline__ unsigned short bfu(float f) {
  __bf16 b = (__bf16)f;
  return __builtin_bit_cast(unsigned short, b);
}
// pre-scaled domain (y = x*log2e): sigmoid(x) = rcp(1 + 2^-y)
static __device__ __forceinline__ float sigm2(float y) {
  return __builtin_amdgcn_rcpf(1.f + exp2_f(-y));
}
// pre-scaled domain (y = 2x*log2e): tanh(x) = 1 - 2*rcp(1 + 2^y)
static __device__ __forceinline__ float tanh2(float y) {
  return fmaf(-2.f, __builtin_amdgcn_rcpf(1.f + exp2_f(y)), 1.f);
}

// ------------------------------------------------------------------
// Row bijection: tile m = g*4+hq (g = gate), tile-row = qp*4+r.
//   hidx(hq,qp,r) = (hq>>1)*32 + qp*8 + (hq&1)*4 + r
// Lane (b,qp)'s D outputs {hidx(hq,qp,r)} == exactly its next-step
// B-fragment slots {c*32+qp*8+j} -> h NEVER leaves the lane: zero
// LDS / shuffle / barrier in the recurrence.
// ------------------------------------------------------------------

// Kernel 0: linearize W (bf16 hi only) into per-lane MFMA A-fragment order,
// pre-scaled into the exp2 domain: i/f/o rows (and bias) * log2e, g rows * 2*log2e.
__global__ void prep_kernel(const float* __restrict__ W_ih, const float* __restrict__ W_hh,
                            const float* __restrict__ b_ih, const float* __restrict__ b_hh,
                            unsigned short* __restrict__ WhhL, unsigned short* __restrict__ WihL,
                            float* __restrict__ bsumL) {
  const int tid = threadIdx.x;  // 256 threads, 1 block
  const int l = tid & 63, qt = tid >> 6;
  const int rowl = l & 15, kq = (l >> 4) * 8;
  for (int mm = 0; mm < 4; ++mm) {
    const int m = qt * 4 + mm;
    const int g = m >> 2, hq = m & 3;
    const float s = (g == 2) ? 2.f * LOG2E : LOG2E;
    const int hidx = (hq >> 1) * 32 + (rowl >> 2) * 8 + (hq & 1) * 4 + (rowl & 3);
    const int orig = g * 64 + hidx;
    for (int c = 0; c < 2; ++c)
      for (int j = 0; j < 8; ++j)
        WhhL[(m * 2 + c) * 512 + l * 8 + j] = bfu(W_hh[orig * 64 + c * 32 + kq + j] * s);
    for (int j = 0; j < 8; ++j)
      WihL[m * 512 + l * 8 + j] = bfu(W_ih[orig * 32 + kq + j] * s);
    if ((l >> 4) == 0) bsumL[m * 16 + rowl] = (b_ih[orig] + b_hh[orig]) * s;
  }
}

// ------------------------------------------------------------------
// Kernel 1: attention. a[b,:] = softmax_d( sum_t x[b,t,d]*w_att[2H+t] )
// (h/c/b_att terms are uniform over d -> softmax-invariant -> dropped).
// ------------------------------------------------------------------
__global__ __launch_bounds__(256) void attn_kernel(const float* __restrict__ x,
                                                   const float* __restrict__ W_att,
                                                   float* __restrict__ out0) {
  int tid = threadIdx.x;
  int b = blockIdx.x * 32 + (tid >> 3);
  int dq = (tid & 7) * 4;
  const float* xb = x + (size_t)b * (TT * DD);
  float px = 0.f, py = 0.f, pz = 0.f, pw = 0.f;
#pragma unroll 4
  for (int t = 0; t < TT; ++t) {
    float w = W_att[2 * HH + t];
    float4 xv = *(const float4*)(xb + t * DD + dq);
    px = fmaf(xv.x, w, px);
    py = fmaf(xv.y, w, py);
    pz = fmaf(xv.z, w, pz);
    pw = fmaf(xv.w, w, pw);
  }
  float m = fmaxf(fmaxf(px, py), fmaxf(pz, pw));
#pragma unroll
  for (int s = 1; s < 8; s <<= 1) m = fmaxf(m, __shfl_xor(m, s));
  float ex = __expf(px - m), ey = __expf(py - m), ez = __expf(pz - m), ew = __expf(pw - m);
  float sum = ex + ey + ez + ew;
#pragma unroll
  for (int s = 1; s < 8; s <<= 1) sum += __shfl_xor(sum, s);
  float inv = __builtin_amdgcn_rcpf(sum);
  float4 a;
  a.x = ex * inv; a.y = ey * inv; a.z = ez * inv; a.w = ew * inv;
  float* o = out0 + (size_t)b * (TT * DD) + dq;
#pragma unroll 4
  for (int t = 0; t < TT; ++t) *(float4*)(o + t * DD) = a;
}

// ------------------------------------------------------------------
// Kernel 2: lane-local LSTM, barrier-free, zero LDS, 48 MFMAs/step.
// 256 blocks x 256 thr = 4 waves/CU (1/SIMD). Each wave owns 16 batch
// rows end-to-end; h stays in-lane via the row bijection. W_hh bf16-hi
// only (lo dropped: recurrence empirically damps bf16-scale noise —
// h is already single-bf16 at absmax 2.4e-4). Registers: whhHi 128
// VGPR ("+v"), wih 64 + bias 64 AGPR ("+a", direct MFMA A/C operands).
// Pointwise in exp2 domain. T-loop unroll forbidden (I$ protection).
// ------------------------------------------------------------------
__global__ __launch_bounds__(256, 1) void lstm_kernel(
    const float* __restrict__ x, const float* __restrict__ h0, const float* __restrict__ c0,
    const float* __restrict__ a_src, const unsigned short* __restrict__ WhhL,
    const unsigned short* __restrict__ WihL, const float* __restrict__ bsumL,
    float* __restrict__ out1) {
  const int tid = threadIdx.x;
  const int l = tid & 63;
  const int wid = tid >> 6;
  const int b = l & 15;
  const int qp = l >> 4;
  const int brow = blockIdx.x * 64 + wid * 16 + b;

  // resident weights: hi -> VGPR; wih, bias -> AGPR
  f32x4 whhHi[16][2], wihR[16], biasR[16];
#pragma unroll
  for (int m = 0; m < 16; ++m) {
#pragma unroll
    for (int c = 0; c < 2; ++c)
      whhHi[m][c] = *(const f32x4*)(WhhL + ((m * 2 + c) << 9) + l * 8);
    wihR[m] = *(const f32x4*)(WihL + (m << 9) + l * 8);
    biasR[m] = *(const f32x4*)(bsumL + m * 16 + qp * 4);
  }
#pragma unroll
  for (int m = 0; m < 16; ++m) {
#pragma unroll
    for (int c = 0; c < 2; ++c) asm volatile("" : "+v"(whhHi[m][c]));
    asm volatile("" : "+a"(wihR[m]));
    asm volatile("" : "+a"(biasR[m]));
  }

  // attention weights for this lane's d-slots (d = qp*8 + j)
  float av[8];
  {
    const float* ap = a_src + (size_t)brow * (TT * DD) + qp * 8;
    float4 a0 = *(const float4*)ap, a1 = *(const float4*)(ap + 4);
    av[0] = a0.x; av[1] = a0.y; av[2] = a0.z; av[3] = a0.w;
    av[4] = a1.x; av[5] = a1.y; av[6] = a1.z; av[7] = a1.w;
  }

  // c state: creg[hq][r] = c[brow][hidx(hq,qp,r)]
  f32x4 creg[4];
#pragma unroll
  for (int hq = 0; hq < 4; ++hq)
    creg[hq] = *(const f32x4*)(c0 + (size_t)brow * HH + (hq >> 1) * 32 + qp * 8 + (hq & 1) * 4);

  // h state as single-bf16 B-fragments: bh[c] elem j = bf16(h[brow][c*32+qp*8+j])
  bf16x8 bh[2];
#pragma unroll
  for (int c = 0; c < 2; ++c) {
    const float* hp = h0 + (size_t)brow * HH + c * 32 + qp * 8;
    float4 v0 = *(const float4*)hp, v1 = *(const float4*)(hp + 4);
    float vv[8] = {v0.x, v0.y, v0.z, v0.w, v1.x, v1.y, v1.z, v1.w};
#pragma unroll
    for (int j = 0; j < 8; ++j) bh[c][j] = (__bf16)vv[j];
  }

  const float* xp = x + (size_t)brow * (TT * DD) + qp * 8;
  float* op = out1 + (size_t)brow * (TT * HH);
  float xv[8];
  {
    float4 x0 = *(const float4*)xp, x1 = *(const float4*)(xp + 4);
    xv[0] = x0.x; xv[1] = x0.y; xv[2] = x0.z; xv[3] = x0.w;
    xv[4] = x1.x; xv[5] = x1.y; xv[6] = x1.z; xv[7] = x1.w;
  }

#pragma unroll 1
  for (int t = 0; t < TT; ++t) {
    // xw for this step (single bf16; lo negligible at |a*x|~0.03)
    bf16x8 bxw;
#pragma unroll
    for (int j = 0; j < 8; ++j) bxw[j] = (__bf16)(xv[j] * av[j]);
    // prefetch next x (clamped; final load is dead but harmless)
    const int tn = (t + 1 < TT) ? (t + 1) : (TT - 1);
    float xn[8];
    {
      const float* xnp = xp + (size_t)tn * DD;
      float4 x0 = *(const float4*)xnp, x1 = *(const float4*)(xnp + 4);
      xn[0] = x0.x; xn[1] = x0.y; xn[2] = x0.z; xn[3] = x0.w;
      xn[4] = x1.x; xn[5] = x1.y; xn[6] = x1.z; xn[7] = x1.w;
    }

    bf16x8 nbh[2];
#pragma unroll
    for (int hq = 0; hq < 4; ++hq) {
      f32x4 acc[4];
#pragma unroll
      for (int g = 0; g < 4; ++g) {
        const int m = g * 4 + hq;
        // bias enters as srcC of the first MFMA, straight from AGPR
        f32x4 A = MFMA(BC(whhHi[m][0]), bh[0], biasR[m]);  // k 0..31
        A = MFMA(BC(whhHi[m][1]), bh[1], A);               // k 32..63
        A = MFMA(BC(wihR[m]), bxw, A);                     // input chunk
        acc[g] = A;
      }
      // pointwise: i/f/g/o lane-local (rows qp*4+r of tiles g*4+hq)
      float hr[4];
#pragma unroll
      for (int r = 0; r < 4; ++r) {
        float ig = sigm2(acc[0][r]);
        float fg = sigm2(acc[1][r]);
        float gt = tanh2(acc[2][r]);   // g rows pre-scaled by 2*log2e
        float og = sigm2(acc[3][r]);
        float cn = fg * creg[hq][r] + ig * gt;
        creg[hq][r] = cn;
        hr[r] = og * tanh2(2.f * LOG2E * cn);
      }
      // out1: contiguous float4 at hidx base (4 qp-lanes cover the full row)
      float4 hv;
      hv.x = hr[0]; hv.y = hr[1]; hv.z = hr[2]; hv.w = hr[3];
      *(float4*)(op + (size_t)t * HH + (hq >> 1) * 32 + qp * 8 + (hq & 1) * 4) = hv;
      // repack into next step's B-fragment (lane-local, single bf16)
#pragma unroll
      for (int r = 0; r < 4; ++r) nbh[hq >> 1][(hq & 1) * 4 + r] = (__bf16)hr[r];
    }
    bh[0] = nbh[0];
    bh[1] = nbh[1];
#pragma unroll
    for (int j = 0; j < 8; ++j) xv[j] = xn[j];
  }
}

extern "C" void kernel_launch(void* const* d_in, const int* in_sizes, int n_in,
                              void* d_out, int out_size, void* d_ws, size_t ws_size,
                              hipStream_t stream) {
  const float* x = (const float*)d_in[0];
  const float* h0 = (const float*)d_in[1];
  const float* c0 = (const float*)d_in[2];
  const float* W_att = (const float*)d_in[3];
  // d_in[4] = b_att: uniform shift, softmax-invariant -> unused
  const float* W_ih = (const float*)d_in[5];
  const float* W_hh = (const float*)d_in[6];
  const float* b_ih = (const float*)d_in[7];
  const float* b_hh = (const float*)d_in[8];

  float* out0 = (float*)d_out;                // attention [B,T,D]
  float* out1 = out0 + (size_t)BB * TT * DD;  // input_encoded [B,T,H]

  char* ws = (char*)d_ws;
  unsigned short* WhhL = (unsigned short*)ws;            // 32768 B (hi only)
  unsigned short* WihL = (unsigned short*)(ws + 32768);  // 16384 B
  float* bsumL = (float*)(ws + 49152);                   // 1024 B

  prep_kernel<<<1, 256, 0, stream>>>(W_ih, W_hh, b_ih, b_hh, WhhL, WihL, bsumL);
  attn_kernel<<<BB / 32, 256, 0, stream>>>(x, W_att, out0);
  // lstm reads a[b,d] from the t=0 slice of out0 (== a broadcast over t)
  lstm_kernel<<<BB / 64, 256, 0, stream>>>(x, h0, c0, out0, WhhL, WihL, bsumL, out1);
}

// Round 14
// 120.998 us; speedup vs baseline: 1.3365x; 1.2076x over previous
//
#include <hip/hip_runtime.h>

#define TT 48
#define DD 32
#define HH 64
#define BB 16384
#define LOG2E 1.4426950408889634f

typedef __bf16 bf16x8 __attribute__((ext_vector_type(8)));
typedef float f32x4 __attribute__((ext_vector_type(4)));

#define MFMA(a, b, c) __builtin_amdgcn_mfma_f32_16x16x32_bf16(a, b, c, 0, 0, 0)
#define BC(v) __builtin_bit_cast(bf16x8, v)

static __device__ __forceinline__ float exp2_f(float v) {
#if __has_builtin(__builtin_amdgcn_exp2f)
  return __builtin_amdgcn_exp2f(v);
#else
  return exp2f(v);
#endif
}
static __device__ __forceinline__ unsigned short bfu(float f) {
  __bf16 b = (__bf16)f;
  return __builtin_bit_cast(unsigned short, b);
}
// pre-scaled domain (y = x*log2e): sigmoid(x) = rcp(1 + 2^-y)
static __device__ __forceinline__ float sigm2(float y) {
  return __builtin_amdgcn_rcpf(1.f + exp2_f(-y));
}
// pre-scaled domain (y = 2x*log2e): tanh(x) = 1 - 2*rcp(1 + 2^y)
static __device__ __forceinline__ float tanh2(float y) {
  return fmaf(-2.f, __builtin_amdgcn_rcpf(1.f + exp2_f(y)), 1.f);
}

// ------------------------------------------------------------------
// Row bijection: tile m = g*4+hq (g = gate), tile-row = qp*4+r.
//   hidx(hq,qp,r) = (hq>>1)*32 + qp*8 + (hq&1)*4 + r
// Lane (b,qp)'s D outputs {hidx(hq,qp,r)} == exactly its next-step
// B-fragment slots {c*32+qp*8+j} -> h NEVER leaves the lane: zero
// LDS / shuffle / barrier in the recurrence.
// ------------------------------------------------------------------

// Kernel 0: linearize W (bf16 hi only) into per-lane MFMA A-fragment order,
// pre-scaled into the exp2 domain: i/f/o rows (and bias) * log2e, g rows * 2*log2e.
__global__ void prep_kernel(const float* __restrict__ W_ih, const float* __restrict__ W_hh,
                            const float* __restrict__ b_ih, const float* __restrict__ b_hh,
                            unsigned short* __restrict__ WhhL, unsigned short* __restrict__ WihL,
                            float* __restrict__ bsumL) {
  const int tid = threadIdx.x;  // 256 threads, 1 block
  const int l = tid & 63, qt = tid >> 6;
  const int rowl = l & 15, kq = (l >> 4) * 8;
  for (int mm = 0; mm < 4; ++mm) {
    const int m = qt * 4 + mm;
    const int g = m >> 2, hq = m & 3;
    const float s = (g == 2) ? 2.f * LOG2E : LOG2E;
    const int hidx = (hq >> 1) * 32 + (rowl >> 2) * 8 + (hq & 1) * 4 + (rowl & 3);
    const int orig = g * 64 + hidx;
    for (int c = 0; c < 2; ++c)
      for (int j = 0; j < 8; ++j)
        WhhL[(m * 2 + c) * 512 + l * 8 + j] = bfu(W_hh[orig * 64 + c * 32 + kq + j] * s);
    for (int j = 0; j < 8; ++j)
      WihL[m * 512 + l * 8 + j] = bfu(W_ih[orig * 32 + kq + j] * s);
    if ((l >> 4) == 0) bsumL[m * 16 + rowl] = (b_ih[orig] + b_hh[orig]) * s;
  }
}

// ------------------------------------------------------------------
// Kernel 1: FUSED attention + lane-local LSTM. 256 blocks x 256 thr
// = 4 waves/CU (1/SIMD). Prologue: each lane accumulates its own
// attention logits p[d] = sum_t x[b,t,d]*w_att[2H+t] for d = qp*8..+8
// (h/c/b_att terms are uniform over d -> softmax-invariant -> dropped),
// softmax over d via 2x shfl_xor across the 4 qp-groups sharing a batch
// row; a stays in registers. out0 (a broadcast over t) is written inside
// the recurrence loop as full-line float4 stores.
// Recurrence: barrier-free, zero LDS, 48 MFMAs/step; h stays in-lane via
// the row bijection; W_hh bf16-hi in 128 VGPR ("+v"), wih+bias in 128
// AGPR ("+a", direct MFMA A/C operands). Pointwise in exp2 domain.
// ------------------------------------------------------------------
__global__ __launch_bounds__(256, 1) void lstm_kernel(
    const float* __restrict__ x, const float* __restrict__ h0, const float* __restrict__ c0,
    const float* __restrict__ W_att, const unsigned short* __restrict__ WhhL,
    const unsigned short* __restrict__ WihL, const float* __restrict__ bsumL,
    float* __restrict__ out0, float* __restrict__ out1) {
  const int tid = threadIdx.x;
  const int l = tid & 63;
  const int wid = tid >> 6;
  const int b = l & 15;
  const int qp = l >> 4;
  const int brow = blockIdx.x * 64 + wid * 16 + b;

  // resident weights: hi -> VGPR; wih, bias -> AGPR
  f32x4 whhHi[16][2], wihR[16], biasR[16];
#pragma unroll
  for (int m = 0; m < 16; ++m) {
#pragma unroll
    for (int c = 0; c < 2; ++c)
      whhHi[m][c] = *(const f32x4*)(WhhL + ((m * 2 + c) << 9) + l * 8);
    wihR[m] = *(const f32x4*)(WihL + (m << 9) + l * 8);
    biasR[m] = *(const f32x4*)(bsumL + m * 16 + qp * 4);
  }
#pragma unroll
  for (int m = 0; m < 16; ++m) {
#pragma unroll
    for (int c = 0; c < 2; ++c) asm volatile("" : "+v"(whhHi[m][c]));
    asm volatile("" : "+a"(wihR[m]));
    asm volatile("" : "+a"(biasR[m]));
  }

  const float* xp = x + (size_t)brow * (TT * DD) + qp * 8;

  // ---- fused attention: logits for this lane's d-slots ----
  float p[8];
#pragma unroll
  for (int j = 0; j < 8; ++j) p[j] = 0.f;
#pragma unroll 4
  for (int t = 0; t < TT; ++t) {
    const float w = W_att[2 * HH + t];
    float4 x0 = *(const float4*)(xp + t * DD);
    float4 x1 = *(const float4*)(xp + t * DD + 4);
    p[0] = fmaf(x0.x, w, p[0]); p[1] = fmaf(x0.y, w, p[1]);
    p[2] = fmaf(x0.z, w, p[2]); p[3] = fmaf(x0.w, w, p[3]);
    p[4] = fmaf(x1.x, w, p[4]); p[5] = fmaf(x1.y, w, p[5]);
    p[6] = fmaf(x1.z, w, p[6]); p[7] = fmaf(x1.w, w, p[7]);
  }
  // softmax over d = 32: lanes l, l^16, l^32, l^48 share a batch row
  float av[8];
  {
    float mx = fmaxf(fmaxf(fmaxf(p[0], p[1]), fmaxf(p[2], p[3])),
                     fmaxf(fmaxf(p[4], p[5]), fmaxf(p[6], p[7])));
    mx = fmaxf(mx, __shfl_xor(mx, 16));
    mx = fmaxf(mx, __shfl_xor(mx, 32));
    float s = 0.f;
#pragma unroll
    for (int j = 0; j < 8; ++j) {
      av[j] = exp2_f((p[j] - mx) * LOG2E);
      s += av[j];
    }
    s += __shfl_xor(s, 16);
    s += __shfl_xor(s, 32);
    float inv = __builtin_amdgcn_rcpf(s);
#pragma unroll
    for (int j = 0; j < 8; ++j) av[j] *= inv;
  }
  float4 av0, av1;
  av0.x = av[0]; av0.y = av[1]; av0.z = av[2]; av0.w = av[3];
  av1.x = av[4]; av1.y = av[5]; av1.z = av[6]; av1.w = av[7];
  float* o0 = out0 + (size_t)brow * (TT * DD) + qp * 8;

  // c state: creg[hq][r] = c[brow][hidx(hq,qp,r)]
  f32x4 creg[4];
#pragma unroll
  for (int hq = 0; hq < 4; ++hq)
    creg[hq] = *(const f32x4*)(c0 + (size_t)brow * HH + (hq >> 1) * 32 + qp * 8 + (hq & 1) * 4);

  // h state as single-bf16 B-fragments: bh[c] elem j = bf16(h[brow][c*32+qp*8+j])
  bf16x8 bh[2];
#pragma unroll
  for (int c = 0; c < 2; ++c) {
    const float* hp = h0 + (size_t)brow * HH + c * 32 + qp * 8;
    float4 v0 = *(const float4*)hp, v1 = *(const float4*)(hp + 4);
    float vv[8] = {v0.x, v0.y, v0.z, v0.w, v1.x, v1.y, v1.z, v1.w};
#pragma unroll
    for (int j = 0; j < 8; ++j) bh[c][j] = (__bf16)vv[j];
  }

  float* op = out1 + (size_t)brow * (TT * HH);
  float xv[8];
  {
    float4 x0 = *(const float4*)xp, x1 = *(const float4*)(xp + 4);
    xv[0] = x0.x; xv[1] = x0.y; xv[2] = x0.z; xv[3] = x0.w;
    xv[4] = x1.x; xv[5] = x1.y; xv[6] = x1.z; xv[7] = x1.w;
  }

#pragma unroll 1
  for (int t = 0; t < TT; ++t) {
    // out0 broadcast write (full 128B line covered by the 4 qp-lanes per row)
    *(float4*)(o0 + t * DD) = av0;
    *(float4*)(o0 + t * DD + 4) = av1;
    // xw for this step (single bf16; lo negligible at |a*x|~0.03)
    bf16x8 bxw;
#pragma unroll
    for (int j = 0; j < 8; ++j) bxw[j] = (__bf16)(xv[j] * av[j]);
    // prefetch next x (clamped; final load is dead but harmless)
    const int tn = (t + 1 < TT) ? (t + 1) : (TT - 1);
    float xn[8];
    {
      const float* xnp = xp + (size_t)tn * DD;
      float4 x0 = *(const float4*)xnp, x1 = *(const float4*)(xnp + 4);
      xn[0] = x0.x; xn[1] = x0.y; xn[2] = x0.z; xn[3] = x0.w;
      xn[4] = x1.x; xn[5] = x1.y; xn[6] = x1.z; xn[7] = x1.w;
    }

    bf16x8 nbh[2];
#pragma unroll
    for (int hq = 0; hq < 4; ++hq) {
      f32x4 acc[4];
#pragma unroll
      for (int g = 0; g < 4; ++g) {
        const int m = g * 4 + hq;
        // bias enters as srcC of the first MFMA, straight from AGPR
        f32x4 A = MFMA(BC(whhHi[m][0]), bh[0], biasR[m]);  // k 0..31
        A = MFMA(BC(whhHi[m][1]), bh[1], A);               // k 32..63
        A = MFMA(BC(wihR[m]), bxw, A);                     // input chunk
        acc[g] = A;
      }
      // pointwise: i/f/g/o lane-local (rows qp*4+r of tiles g*4+hq)
      float hr[4];
#pragma unroll
      for (int r = 0; r < 4; ++r) {
        float ig = sigm2(acc[0][r]);
        float fg = sigm2(acc[1][r]);
        float gt = tanh2(acc[2][r]);   // g rows pre-scaled by 2*log2e
        float og = sigm2(acc[3][r]);
        float cn = fg * creg[hq][r] + ig * gt;
        creg[hq][r] = cn;
        hr[r] = og * tanh2(2.f * LOG2E * cn);
      }
      // out1: contiguous float4 at hidx base (4 qp-lanes cover the full row)
      float4 hv;
      hv.x = hr[0]; hv.y = hr[1]; hv.z = hr[2]; hv.w = hr[3];
      *(float4*)(op + (size_t)t * HH + (hq >> 1) * 32 + qp * 8 + (hq & 1) * 4) = hv;
      // repack into next step's B-fragment (lane-local, single bf16)
#pragma unroll
      for (int r = 0; r < 4; ++r) nbh[hq >> 1][(hq & 1) * 4 + r] = (__bf16)hr[r];
    }
    bh[0] = nbh[0];
    bh[1] = nbh[1];
#pragma unroll
    for (int j = 0; j < 8; ++j) xv[j] = xn[j];
  }
}

extern "C" void kernel_launch(void* const* d_in, const int* in_sizes, int n_in,
                              void* d_out, int out_size, void* d_ws, size_t ws_size,
                              hipStream_t stream) {
  const float* x = (const float*)d_in[0];
  const float* h0 = (const float*)d_in[1];
  const float* c0 = (const float*)d_in[2];
  const float* W_att = (const float*)d_in[3];
  // d_in[4] = b_att: uniform shift, softmax-invariant -> unused
  const float* W_ih = (const float*)d_in[5];
  const float* W_hh = (const float*)d_in[6];
  const float* b_ih = (const float*)d_in[7];
  const float* b_hh = (const float*)d_in[8];

  float* out0 = (float*)d_out;                // attention [B,T,D]
  float* out1 = out0 + (size_t)BB * TT * DD;  // input_encoded [B,T,H]

  char* ws = (char*)d_ws;
  unsigned short* WhhL = (unsigned short*)ws;            // 32768 B (hi only)
  unsigned short* WihL = (unsigned short*)(ws + 32768);  // 16384 B
  float* bsumL = (float*)(ws + 49152);                   // 1024 B

  prep_kernel<<<1, 256, 0, stream>>>(W_ih, W_hh, b_ih, b_hh, WhhL, WihL, bsumL);
  lstm_kernel<<<BB / 64, 256, 0, stream>>>(x, h0, c0, W_att, WhhL, WihL, bsumL, out0, out1);
}

// Round 15
// 120.047 us; speedup vs baseline: 1.3471x; 1.0079x over previous
//
#include <hip/hip_runtime.h>

#define TT 48
#define DD 32
#define HH 64
#define BB 16384
#define LOG2E 1.4426950408889634f

typedef __bf16 bf16x8 __attribute__((ext_vector_type(8)));
typedef float f32x4 __attribute__((ext_vector_type(4)));

#define MFMA(a, b, c) __builtin_amdgcn_mfma_f32_16x16x32_bf16(a, b, c, 0, 0, 0)
#define BC(v) __builtin_bit_cast(bf16x8, v)

static __device__ __forceinline__ float exp2_f(float v) {
#if __has_builtin(__builtin_amdgcn_exp2f)
  return __builtin_amdgcn_exp2f(v);
#else
  return exp2f(v);
#endif
}
static __device__ __forceinline__ unsigned short bfu(float f) {
  __bf16 b = (__bf16)f;
  return __builtin_bit_cast(unsigned short, b);
}
// pre-scaled domain (y = x*log2e): sigmoid(x) = rcp(1 + 2^-y)
static __device__ __forceinline__ float sigm2(float y) {
  return __builtin_amdgcn_rcpf(1.f + exp2_f(-y));
}
// pre-scaled domain (y = 2x*log2e): tanh(x) = 1 - 2*rcp(1 + 2^y)
static __device__ __forceinline__ float tanh2(float y) {
  return fmaf(-2.f, __builtin_amdgcn_rcpf(1.f + exp2_f(y)), 1.f);
}

// ------------------------------------------------------------------
// Row bijection: tile m = g*4+hq (g = gate), tile-row = qp*4+r.
//   hidx(hq,qp,r) = (hq>>1)*32 + qp*8 + (hq&1)*4 + r
// Lane (b,qp)'s D outputs == exactly its next-step B-fragment slots ->
// h NEVER leaves the lane: zero LDS / shuffle / barrier in the recurrence.
// ------------------------------------------------------------------

// Kernel 0: linearize W (bf16 hi only) into per-lane MFMA A-fragment order,
// pre-scaled into the exp2 domain: i/f/o rows (and bias) * log2e, g rows * 2*log2e.
__global__ void prep_kernel(const float* __restrict__ W_ih, const float* __restrict__ W_hh,
                            const float* __restrict__ b_ih, const float* __restrict__ b_hh,
                            unsigned short* __restrict__ WhhL, unsigned short* __restrict__ WihL,
                            float* __restrict__ bsumL) {
  const int tid = threadIdx.x;  // 256 threads, 1 block
  const int l = tid & 63, qt = tid >> 6;
  const int rowl = l & 15, kq = (l >> 4) * 8;
  for (int mm = 0; mm < 4; ++mm) {
    const int m = qt * 4 + mm;
    const int g = m >> 2, hq = m & 3;
    const float s = (g == 2) ? 2.f * LOG2E : LOG2E;
    const int hidx = (hq >> 1) * 32 + (rowl >> 2) * 8 + (hq & 1) * 4 + (rowl & 3);
    const int orig = g * 64 + hidx;
    for (int c = 0; c < 2; ++c)
      for (int j = 0; j < 8; ++j)
        WhhL[(m * 2 + c) * 512 + l * 8 + j] = bfu(W_hh[orig * 64 + c * 32 + kq + j] * s);
    for (int j = 0; j < 8; ++j)
      WihL[m * 512 + l * 8 + j] = bfu(W_ih[orig * 32 + kq + j] * s);
    if ((l >> 4) == 0) bsumL[m * 16 + rowl] = (b_ih[orig] + b_hh[orig]) * s;
  }
}

// One LSTM step. x-MFMA is FIRST in each accumulation chain (no h
// dependency -> hoistable into the previous step's pointwise phase).
// xv is consumed for bxw, then reused as the prefetch buffer for t+2.
// c is carried in the 2*log2e domain (saves one mul per element).
static __device__ __forceinline__ void lstm_step(
    const int t, const float* __restrict__ xp, float* __restrict__ o0,
    float* __restrict__ opq, const float* av, float* xv,
    const f32x4 (&whhHi)[16][2], const f32x4 (&wihR)[16], const f32x4 (&biasR)[16],
    f32x4 (&creg)[4], bf16x8 (&bhIn)[2], bf16x8 (&bhOut)[2],
    const float4 av0, const float4 av1) {
  // out0 broadcast write (full 128B line covered by the 4 qp-lanes per row)
  *(float4*)(o0 + t * DD) = av0;
  *(float4*)(o0 + t * DD + 4) = av1;
  // xw fragment for this step
  bf16x8 bxw;
#pragma unroll
  for (int j = 0; j < 8; ++j) bxw[j] = (__bf16)(xv[j] * av[j]);
  // prefetch x[t+2] into the freed buffer (clamped; dead at the tail)
  const int tn = (t + 2 < TT) ? (t + 2) : (TT - 1);
  {
    const float* xnp = xp + (size_t)tn * DD;
    float4 x0 = *(const float4*)xnp, x1 = *(const float4*)(xnp + 4);
    xv[0] = x0.x; xv[1] = x0.y; xv[2] = x0.z; xv[3] = x0.w;
    xv[4] = x1.x; xv[5] = x1.y; xv[6] = x1.z; xv[7] = x1.w;
  }
#pragma unroll
  for (int hq = 0; hq < 4; ++hq) {
    f32x4 acc[4];
#pragma unroll
    for (int g = 0; g < 4; ++g) {
      const int m = g * 4 + hq;
      f32x4 A = MFMA(BC(wihR[m]), bxw, biasR[m]);  // x chunk FIRST (no h dep)
      A = MFMA(BC(whhHi[m][0]), bhIn[0], A);       // k 0..31
      A = MFMA(BC(whhHi[m][1]), bhIn[1], A);       // k 32..63
      acc[g] = A;
    }
    // pointwise: i/f/g/o lane-local (rows qp*4+r of tiles g*4+hq)
    float hr[4];
#pragma unroll
    for (int r = 0; r < 4; ++r) {
      float ig = sigm2(acc[0][r]);
      float fg = sigm2(acc[1][r]);
      // gt' = 2*log2e*tanh(g) (g rows pre-scaled by 2*log2e)
      float gts = fmaf(-4.f * LOG2E,
                       __builtin_amdgcn_rcpf(1.f + exp2_f(acc[2][r])), 2.f * LOG2E);
      float og = sigm2(acc[3][r]);
      float cns = fmaf(fg, creg[hq][r], ig * gts);  // c' = 2*log2e*c
      creg[hq][r] = cns;
      hr[r] = og * tanh2(cns);
    }
    // out1: contiguous float4 at hidx base (4 qp-lanes cover the full row)
    float4 hv;
    hv.x = hr[0]; hv.y = hr[1]; hv.z = hr[2]; hv.w = hr[3];
    *(float4*)(opq + (size_t)t * HH + (hq >> 1) * 32 + (hq & 1) * 4) = hv;
    // repack into next step's B-fragment (lane-local, single bf16)
#pragma unroll
    for (int r = 0; r < 4; ++r) bhOut[hq >> 1][(hq & 1) * 4 + r] = (__bf16)hr[r];
  }
}

// ------------------------------------------------------------------
// Kernel 1: FUSED attention + lane-local LSTM. 256 blocks x 256 thr
// = 4 waves/CU (1/SIMD). Barrier-free, zero LDS, 48 MFMAs/step.
// W_hh bf16-hi in 128 VGPR ("+v"); wih+bias in 128 AGPR ("+a", direct
// MFMA A/C operands). Main loop manually unrolled 2x with register
// double-buffers (xvA/xvB, bhA/bhB) — no copies, 2-step sched window.
// ------------------------------------------------------------------
__global__ __launch_bounds__(256, 1) void lstm_kernel(
    const float* __restrict__ x, const float* __restrict__ h0, const float* __restrict__ c0,
    const float* __restrict__ W_att, const unsigned short* __restrict__ WhhL,
    const unsigned short* __restrict__ WihL, const float* __restrict__ bsumL,
    float* __restrict__ out0, float* __restrict__ out1) {
  const int tid = threadIdx.x;
  const int l = tid & 63;
  const int wid = tid >> 6;
  const int b = l & 15;
  const int qp = l >> 4;
  const int brow = blockIdx.x * 64 + wid * 16 + b;

  // resident weights: hi -> VGPR; wih, bias -> AGPR
  f32x4 whhHi[16][2], wihR[16], biasR[16];
#pragma unroll
  for (int m = 0; m < 16; ++m) {
#pragma unroll
    for (int c = 0; c < 2; ++c)
      whhHi[m][c] = *(const f32x4*)(WhhL + ((m * 2 + c) << 9) + l * 8);
    wihR[m] = *(const f32x4*)(WihL + (m << 9) + l * 8);
    biasR[m] = *(const f32x4*)(bsumL + m * 16 + qp * 4);
  }
#pragma unroll
  for (int m = 0; m < 16; ++m) {
#pragma unroll
    for (int c = 0; c < 2; ++c) asm volatile("" : "+v"(whhHi[m][c]));
    asm volatile("" : "+a"(wihR[m]));
    asm volatile("" : "+a"(biasR[m]));
  }

  const float* xp = x + (size_t)brow * (TT * DD) + qp * 8;

  // ---- fused attention: logits for this lane's d-slots ----
  float p[8];
#pragma unroll
  for (int j = 0; j < 8; ++j) p[j] = 0.f;
#pragma unroll 4
  for (int t = 0; t < TT; ++t) {
    const float w = W_att[2 * HH + t];
    float4 x0 = *(const float4*)(xp + t * DD);
    float4 x1 = *(const float4*)(xp + t * DD + 4);
    p[0] = fmaf(x0.x, w, p[0]); p[1] = fmaf(x0.y, w, p[1]);
    p[2] = fmaf(x0.z, w, p[2]); p[3] = fmaf(x0.w, w, p[3]);
    p[4] = fmaf(x1.x, w, p[4]); p[5] = fmaf(x1.y, w, p[5]);
    p[6] = fmaf(x1.z, w, p[6]); p[7] = fmaf(x1.w, w, p[7]);
  }
  // softmax over d = 32: lanes l, l^16, l^32, l^48 share a batch row
  float av[8];
  {
    float mx = fmaxf(fmaxf(fmaxf(p[0], p[1]), fmaxf(p[2], p[3])),
                     fmaxf(fmaxf(p[4], p[5]), fmaxf(p[6], p[7])));
    mx = fmaxf(mx, __shfl_xor(mx, 16));
    mx = fmaxf(mx, __shfl_xor(mx, 32));
    float s = 0.f;
#pragma unroll
    for (int j = 0; j < 8; ++j) {
      av[j] = exp2_f((p[j] - mx) * LOG2E);
      s += av[j];
    }
    s += __shfl_xor(s, 16);
    s += __shfl_xor(s, 32);
    float inv = __builtin_amdgcn_rcpf(s);
#pragma unroll
    for (int j = 0; j < 8; ++j) av[j] *= inv;
  }
  float4 av0, av1;
  av0.x = av[0]; av0.y = av[1]; av0.z = av[2]; av0.w = av[3];
  av1.x = av[4]; av1.y = av[5]; av1.z = av[6]; av1.w = av[7];
  float* o0 = out0 + (size_t)brow * (TT * DD) + qp * 8;

  // c state in the 2*log2e domain: creg[hq][r] = 2*log2e * c[brow][hidx(hq,qp,r)]
  f32x4 creg[4];
#pragma unroll
  for (int hq = 0; hq < 4; ++hq) {
    f32x4 cv = *(const f32x4*)(c0 + (size_t)brow * HH + (hq >> 1) * 32 + qp * 8 + (hq & 1) * 4);
#pragma unroll
    for (int r = 0; r < 4; ++r) cv[r] *= 2.f * LOG2E;
    creg[hq] = cv;
  }

  // h state as single-bf16 B-fragments
  bf16x8 bhA[2], bhB[2];
#pragma unroll
  for (int c = 0; c < 2; ++c) {
    const float* hp = h0 + (size_t)brow * HH + c * 32 + qp * 8;
    float4 v0 = *(const float4*)hp, v1 = *(const float4*)(hp + 4);
    float vv[8] = {v0.x, v0.y, v0.z, v0.w, v1.x, v1.y, v1.z, v1.w};
#pragma unroll
    for (int j = 0; j < 8; ++j) bhA[c][j] = (__bf16)vv[j];
  }

  float* opq = out1 + (size_t)brow * (TT * HH) + qp * 8;
  float xvA[8], xvB[8];
  {
    float4 x0 = *(const float4*)xp, x1 = *(const float4*)(xp + 4);
    xvA[0] = x0.x; xvA[1] = x0.y; xvA[2] = x0.z; xvA[3] = x0.w;
    xvA[4] = x1.x; xvA[5] = x1.y; xvA[6] = x1.z; xvA[7] = x1.w;
    float4 y0 = *(const float4*)(xp + DD), y1 = *(const float4*)(xp + DD + 4);
    xvB[0] = y0.x; xvB[1] = y0.y; xvB[2] = y0.z; xvB[3] = y0.w;
    xvB[4] = y1.x; xvB[5] = y1.y; xvB[6] = y1.z; xvB[7] = y1.w;
  }

#pragma unroll 1
  for (int t = 0; t < TT; t += 2) {
    lstm_step(t, xp, o0, opq, av, xvA, whhHi, wihR, biasR, creg, bhA, bhB, av0, av1);
    lstm_step(t + 1, xp, o0, opq, av, xvB, whhHi, wihR, biasR, creg, bhB, bhA, av0, av1);
  }
}

extern "C" void kernel_launch(void* const* d_in, const int* in_sizes, int n_in,
                              void* d_out, int out_size, void* d_ws, size_t ws_size,
                              hipStream_t stream) {
  const float* x = (const float*)d_in[0];
  const float* h0 = (const float*)d_in[1];
  const float* c0 = (const float*)d_in[2];
  const float* W_att = (const float*)d_in[3];
  // d_in[4] = b_att: uniform shift, softmax-invariant -> unused
  const float* W_ih = (const float*)d_in[5];
  const float* W_hh = (const float*)d_in[6];
  const float* b_ih = (const float*)d_in[7];
  const float* b_hh = (const float*)d_in[8];

  float* out0 = (float*)d_out;                // attention [B,T,D]
  float* out1 = out0 + (size_t)BB * TT * DD;  // input_encoded [B,T,H]

  char* ws = (char*)d_ws;
  unsigned short* WhhL = (unsigned short*)ws;            // 32768 B (hi only)
  unsigned short* WihL = (unsigned short*)(ws + 32768);  // 16384 B
  float* bsumL = (float*)(ws + 49152);                   // 1024 B

  prep_kernel<<<1, 256, 0, stream>>>(W_ih, W_hh, b_ih, b_hh, WhhL, WihL, bsumL);
  lstm_kernel<<<BB / 64, 256, 0, stream>>>(x, h0, c0, W_att, WhhL, WihL, bsumL, out0, out1);
}